// Round 10
// baseline (60.129 us; speedup 1.0000x reference)
//
#include <hip/hip_runtime.h>
#include <hip/hip_bf16.h>

// MultiScaleSparseSelfAttention, algebraically reduced:
//  - roll acts on (head, flatN) axes; softmax is shift-invariant over keys
//  - sum over dw collapses to P_{h,g} @ Wsum_u, Wsum = sum of v rows at {-4,-2,0,2,4}
//  - dh=+2 and dh=-2 identical (mod 4) -> weight 2
// R4: fragment-contiguous layouts; R5: 32 q-rows/wave; R6: swapped-operand
//     attention; R7: LDS-staged proj stores, KS=1; R8: normalized bf16 pv
//     slots, coalesced epilogue, setprio (47.9 us).
// R9 (atomicAdd out): REGRESSED 55.4 — reverted.
// R10: R8 + attn occupancy fix: 16 q-rows/wave, 1024 blocks -> 4 blocks/CU
//      (4 waves/SIMD, was 2) to hide the exp-chain latency.

typedef __bf16 bf16x8 __attribute__((ext_vector_type(8)));
typedef __bf16 bf16x4 __attribute__((ext_vector_type(4)));
typedef float f32x4 __attribute__((ext_vector_type(4)));

#define MFMA16(A,B,C) __builtin_amdgcn_mfma_f32_16x16x32_bf16(A,B,C,0,0,0)

__device__ __forceinline__ bf16x8 ld8(const __bf16* p){ return *reinterpret_cast<const bf16x8*>(p); }

struct ProjArgs { const float* W[6]; const float* Bz[6]; };

// ---- cvt: f32 -> bf16 in FRAGMENT order. X: 2x(2048x256), W: 6x(256x256) ----
__global__ __launch_bounds__(256) void cvt_k(const float* __restrict__ x0,
                                             const float* __restrict__ x1,
                                             ProjArgs args,
                                             __bf16* __restrict__ Xb,
                                             __bf16* __restrict__ Wb)
{
    int g = blockIdx.x*256 + threadIdx.x;
    const float* src; __bf16* dst;
    if (g < 131072){                           // X part: s = g>>16
        int s = g >> 16;
        int E = (g & 65535)*8;                 // element offset within scale
        int blk = E >> 9, lane8 = (E >> 3) & 63;
        int row = (blk>>3)*16 + (lane8 & 15);
        int ci  = (blk&7)*32 + (lane8>>4)*8;
        src = (s ? x1 : x0) + (size_t)row*256 + ci;
        dst = Xb + (size_t)s*524288 + E;
    } else {
        int gw = g - 131072;                   // W part: sp = gw>>13
        int sp = gw >> 13;
        int E = (gw & 8191)*8;
        int blk = E >> 9, lane8 = (E >> 3) & 63;
        int co = (blk>>3)*16 + (lane8 & 15);
        int ci = (blk&7)*32 + (lane8>>4)*8;
        src = args.W[sp] + (size_t)co*256 + ci;
        dst = Wb + (size_t)sp*65536 + E;
    }
    f32x4 a = *reinterpret_cast<const f32x4*>(src);
    f32x4 b = *reinterpret_cast<const f32x4*>(src+4);
    bf16x8 o;
    #pragma unroll
    for (int j=0;j<4;j++){ o[j] = (__bf16)a[j]; o[4+j] = (__bf16)b[j]; }
    *reinterpret_cast<bf16x8*>(dst) = o;
}

// ---------------- projection ----------------
// Each block computes a 64x64 tile of q|k|v, stages in LDS (fragment order
// for q/k, natural for v), writes ONE contiguous 8KB region.
__global__ __launch_bounds__(256) void proj_k(const __bf16* __restrict__ Xb,
                                              const __bf16* __restrict__ Wb,
                                              ProjArgs args,
                                              __bf16* __restrict__ Qb,
                                              __bf16* __restrict__ Kb,
                                              __bf16* __restrict__ Vb)
{
    __shared__ __bf16 stage[4096];
    int bid = blockIdx.x;
    int cg = bid % 12, rg = bid / 12;
    int tid = threadIdx.x, wv = tid >> 6, l = tid & 63;
    int lr = l & 15, lg = l >> 4;
    int s = rg >> 5;
    const __bf16* Xf = Xb + (size_t)s*524288;
    int p = cg >> 2;                       // 0=q 1=k 2=v
    const __bf16* Wf = Wb + (size_t)(s*3+p)*65536;
    const float* bp = args.Bz[s*3 + p];
    int colbase = (cg & 3)*64;
    int rowblk = ((rg & 31)*4 + wv);

    f32x4 acc[4];
    #pragma unroll
    for (int t=0;t<4;t++) acc[t] = f32x4{0.f,0.f,0.f,0.f};

    #pragma unroll
    for (int kk=0; kk<8; kk++){
        bf16x8 af = ld8(Xf + (size_t)(rowblk*8 + kk)*512 + l*8);
        #pragma unroll
        for (int ct=0; ct<4; ct++){
            bf16x8 bfv = ld8(Wf + (size_t)(((cg&3)*4 + ct)*8 + kk)*512 + l*8);
            acc[ct] = MFMA16(af, bfv, acc[ct]);
        }
    }
    float qs = (p==0) ? 0.09016844136f : 1.0f;   // (1/16)*log2(e) into Q
    #pragma unroll
    for (int ct=0; ct<4; ct++){
        int d = ct*16 + lr;                      // 0..63 within head
        float bias = bp[colbase + d];
        #pragma unroll
        for (int i=0;i<4;i++){
            float v = (acc[ct][i] + bias) * qs;
            int a;
            if (p < 2) a = wv*1024 + ((d>>5)&1)*512 + ((d>>3)&3)*128 + (lg*4+i)*8 + (d&7);
            else       a = (wv*16 + lg*4 + i)*64 + d;
            stage[a] = (__bf16)v;
        }
    }
    __syncthreads();
    int gr0 = rg*64;
    int b = (gr0 >> 10) & 1, n0 = gr0 & 1023;
    int h = cg & 3;
    int sb = s*2 + b;
    __bf16* dstb; size_t goff;
    if (p == 0){ dstb = Qb; goff = ((size_t)(sb*4 + h))*65536 + (size_t)(n0>>4)*1024; }
    else if (p == 1){ dstb = Kb; goff = ((size_t)(sb*4 + h))*65536 + (size_t)(n0>>4)*1024; }
    else { dstb = Vb; goff = ((size_t)(sb*4 + h)*1024 + n0)*64; }
    bf16x8 v0 = *reinterpret_cast<const bf16x8*>(stage + tid*16);
    bf16x8 v1 = *reinterpret_cast<const bf16x8*>(stage + tid*16 + 8);
    *reinterpret_cast<bf16x8*>(dstb + goff + (size_t)tid*16)     = v0;
    *reinterpret_cast<bf16x8*>(dstb + goff + (size_t)tid*16 + 8) = v1;
}

// ------ smoothed V^T, sigma-permuted A-fragment order: Wsig[sbu] ------
__global__ __launch_bounds__(256) void smooth_k(const __bf16* __restrict__ Vb,
                                                __bf16* __restrict__ WT)
{
    __shared__ __bf16 Vt[72][66];
    int bid = blockIdx.x;
    int sbu = bid >> 4, n0 = (bid & 15)*64;
    int tid = threadIdx.x;
    const __bf16* Vs = Vb + (size_t)sbu*65536;
    for (int idx = tid; idx < 576; idx += 256){
        int row = idx >> 3, ch = idx & 7;
        int n = (n0 - 4 + row) & 1023;
        bf16x8 v = ld8(Vs + (size_t)n*64 + ch*8);
        #pragma unroll
        for (int j=0;j<8;j++) Vt[row][ch*8+j] = v[j];
    }
    __syncthreads();
    int w = tid >> 6, l = tid & 63;
    __bf16* dst = WT + (size_t)sbu*65536;
    int m = n0 + l;
    int kb = m >> 5, m32 = m & 31;
    int p = (m32 < 16) ? ((m32>>2)*8 + (m32&3))
                       : (((m32-16)>>2)*8 + 4 + (m32&3));
    size_t pbase = (size_t)kb*2048 + (p>>3)*128 + (p&7);
    #pragma unroll
    for (int it=0; it<16; it++){
        int d = it*4 + w;
        float sum = 0.f;
        #pragma unroll
        for (int j=0;j<5;j++) sum += (float)Vt[l + j*2][d];
        dst[pbase + (size_t)(d>>4)*512 + (d&15)*8] = (__bf16)sum;
    }
}

// ---------------- attention (swapped operands, full-K, normalized out) -------
// Block task = (s,b,h,dhi,qg): 4 waves x 16 q-rows, 1024 keys. 1024 blocks
// -> 4 blocks/CU -> 4 waves/SIMD (latency hiding for the exp chain).
// S^T = mfma(K,Q); exp -> pack -> B-fragment; O^T = mfma(Wsig_dt, P).
__global__ __launch_bounds__(256) void attn_k(const __bf16* __restrict__ Qb,
                                              const __bf16* __restrict__ Kb,
                                              const __bf16* __restrict__ WT,
                                              __bf16* __restrict__ pvp)
{
    int tid = threadIdx.x, wv = tid>>6, l = tid&63, lr = l&15, lg = l>>4;
    int t = blockIdx.x;
    int qg = t & 15; t >>= 4;
    int dhi = t & 3, h = (t>>2)&3, b = (t>>4)&1, s = (t>>5)&1;
    int dhv = (dhi==2) ? -1 : (dhi==3 ? 2 : dhi);   // {0,1,-1,2}
    int g = (h - dhv + 4) & 3;                      // K head
    int u = (h + dhv + 4) & 3;                      // V head
    int sb = s*2 + b;
    int nbase = qg*64 + wv*16;
    const __bf16* Qw = Qb + ((size_t)(sb*4 + h))*65536 + (size_t)(nbase>>4)*1024;
    const __bf16* Kg = Kb + ((size_t)(sb*4 + g))*65536;
    const __bf16* Wu = WT + ((size_t)(sb*4 + u))*65536;
    bf16x8 qa0 = ld8(Qw + l*8), qa1 = ld8(Qw + 512 + l*8);

    const f32x4 z = {0.f,0.f,0.f,0.f};
    f32x4 pvA[4] = {z,z,z,z};
    float dsA = 0.f;

    #pragma unroll 2
    for (int kt=0; kt<1024; kt+=32){
        const __bf16* k0 = Kg + (size_t)(kt>>4)*1024 + l*8;
        bf16x8 kf00 = ld8(k0),        kf01 = ld8(k0 + 512);
        bf16x8 kf10 = ld8(k0 + 1024), kf11 = ld8(k0 + 1536);
        const __bf16* w0 = Wu + (size_t)(kt>>5)*2048 + l*8;
        bf16x8 wd0 = ld8(w0);
        bf16x8 wd1 = ld8(w0 + 512);
        bf16x8 wd2 = ld8(w0 + 1024);
        bf16x8 wd3 = ld8(w0 + 1536);
        __builtin_amdgcn_s_setprio(1);
        f32x4 sA0 = MFMA16(kf00, qa0, z); sA0 = MFMA16(kf01, qa1, sA0);
        f32x4 sA1 = MFMA16(kf10, qa0, z); sA1 = MFMA16(kf11, qa1, sA1);
        __builtin_amdgcn_s_setprio(0);
        bf16x8 paA;
        #pragma unroll
        for (int i=0;i<4;i++){
            float eA0 = __builtin_amdgcn_exp2f(sA0[i]);
            float eA1 = __builtin_amdgcn_exp2f(sA1[i]);
            dsA += eA0 + eA1;
            paA[i] = (__bf16)eA0; paA[4+i] = (__bf16)eA1;
        }
        __builtin_amdgcn_s_setprio(1);
        pvA[0] = MFMA16(wd0, paA, pvA[0]);
        pvA[1] = MFMA16(wd1, paA, pvA[1]);
        pvA[2] = MFMA16(wd2, paA, pvA[2]);
        pvA[3] = MFMA16(wd3, paA, pvA[3]);
        __builtin_amdgcn_s_setprio(0);
    }
    dsA += __shfl_xor(dsA, 16, 64); dsA += __shfl_xor(dsA, 32, 64);
    float wgt = (dhi==3) ? 2.f : 1.f;
    float invA = wgt / dsA;

    // stage normalized O-tile (16 rows x 64 cols) per wave, stride 72
    __shared__ alignas(16) __bf16 ost[4][16*72];
    __bf16* S = ost[wv];
    #pragma unroll
    for (int dt=0; dt<4; dt++){
        bf16x4 oA;
        #pragma unroll
        for (int i=0;i<4;i++){ oA[i] = (__bf16)(pvA[dt][i]*invA); }
        *reinterpret_cast<bf16x4*>(S + lr*72 + dt*16 + lg*4) = oA;
    }
    int slot = s*4 + dhi;
    __bf16* pp = pvp + (size_t)slot*524288 + (size_t)b*262144 + (size_t)h*64;
    #pragma unroll
    for (int it=0; it<2; it++){
        int r = it*8 + (l>>3);
        bf16x8 v = *reinterpret_cast<const bf16x8*>(S + r*72 + (l&7)*8);
        *reinterpret_cast<bf16x8*>(pp + (size_t)(nbase + r)*256 + (l&7)*8) = v;
    }
}

// ------- reduce: out[b][n][c] = sum over 8 normalized slots ------------
__global__ __launch_bounds__(256) void reduce_k(const __bf16* __restrict__ pvp,
                                                float* __restrict__ out)
{
    int idx = blockIdx.x*256 + threadIdx.x;        // 0..65535
    size_t off = (size_t)idx*8;
    float acc[8] = {0,0,0,0,0,0,0,0};
    #pragma unroll
    for (int s4=0; s4<8; s4++){
        bf16x8 v = ld8(pvp + (size_t)s4*524288 + off);
        #pragma unroll
        for (int j=0;j<8;j++) acc[j] += (float)v[j];
    }
    f32x4 o0 = {acc[0],acc[1],acc[2],acc[3]};
    f32x4 o1 = {acc[4],acc[5],acc[6],acc[7]};
    *reinterpret_cast<f32x4*>(out + off)     = o0;
    *reinterpret_cast<f32x4*>(out + off + 4) = o1;
}

extern "C" void kernel_launch(void* const* d_in, const int* in_sizes, int n_in,
                              void* d_out, int out_size, void* d_ws, size_t ws_size,
                              hipStream_t stream)
{
    const float* x0 = (const float*)d_in[0];
    const float* x1 = (const float*)d_in[1];
    ProjArgs pa;
    for (int s=0;s<2;s++) for (int p=0;p<3;p++){
        pa.W[s*3+p]  = (const float*)d_in[2 + s*6 + p*2];
        pa.Bz[s*3+p] = (const float*)d_in[3 + s*6 + p*2];
    }
    char* wsb = (char*)d_ws;
    __bf16* Qb = (__bf16*)(wsb);                 // 2 MB (fragment order)
    __bf16* Kb = (__bf16*)(wsb + (2u<<20));      // 2 MB (fragment order)
    __bf16* Vb = (__bf16*)(wsb + (4u<<20));      // 2 MB (natural)
    __bf16* WT = (__bf16*)(wsb + (6u<<20));      // 2 MB (sigma fragment order)
    __bf16* Xb = (__bf16*)(wsb + (8u<<20));      // 2 MB (fragment order)
    __bf16* Wb = (__bf16*)(wsb + (10u<<20));     // 0.75 MB (fragment order)
    __bf16* pvp = (__bf16*)(wsb + (11u<<20));    // 8 MB (bf16, 8 normalized slots)

    cvt_k<<<704, 256, 0, stream>>>(x0, x1, pa, Xb, Wb);
    proj_k<<<768, 256, 0, stream>>>(Xb, Wb, pa, Qb, Kb, Vb);
    smooth_k<<<256, 256, 0, stream>>>(Vb, WT);
    attn_k<<<1024, 256, 0, stream>>>(Qb, Kb, WT, pvp);
    reduce_k<<<256, 256, 0, stream>>>(pvp, (float*)d_out);
}

// Round 11
// 48.768 us; speedup vs baseline: 1.2330x; 1.2330x over previous
//
#include <hip/hip_runtime.h>
#include <hip/hip_bf16.h>

// MultiScaleSparseSelfAttention, algebraically reduced:
//  - roll acts on (head, flatN) axes; softmax is shift-invariant over keys
//  - sum over dw collapses to P_{h,g} @ Wsum_u, Wsum = sum of v rows at {-4,-2,0,2,4}
//  - dh=+2 and dh=-2 identical (mod 4) -> weight 2
// R4: fragment layouts; R5: 32 q-rows/wave; R6: swapped-operand attention;
// R7: LDS-staged proj stores, KS=1; R8: normalized bf16 pv slots, coalesced
//     epilogue (47.9 us = best).
// R9 atomicAdd-out: REGRESSED 55.4. R10 16-row/wave occupancy: REGRESSED 60.1
//     (doubled stream traffic, halved ILP). Both reverted.
// R11: R8 + attn-only: manual register double-buffer (loads issue one full
//      compute phase early), NO setprio (T5 null outside phase-split),
//      __syncthreads per 64-key macro-iter to keep the block's 4 waves
//      converged on their shared K/W stream (L1 dedupe -> L2 traffic /4).

typedef __bf16 bf16x8 __attribute__((ext_vector_type(8)));
typedef __bf16 bf16x4 __attribute__((ext_vector_type(4)));
typedef float f32x4 __attribute__((ext_vector_type(4)));

#define MFMA16(A,B,C) __builtin_amdgcn_mfma_f32_16x16x32_bf16(A,B,C,0,0,0)

__device__ __forceinline__ bf16x8 ld8(const __bf16* p){ return *reinterpret_cast<const bf16x8*>(p); }

struct ProjArgs { const float* W[6]; const float* Bz[6]; };

// ---- cvt: f32 -> bf16 in FRAGMENT order. X: 2x(2048x256), W: 6x(256x256) ----
__global__ __launch_bounds__(256) void cvt_k(const float* __restrict__ x0,
                                             const float* __restrict__ x1,
                                             ProjArgs args,
                                             __bf16* __restrict__ Xb,
                                             __bf16* __restrict__ Wb)
{
    int g = blockIdx.x*256 + threadIdx.x;
    const float* src; __bf16* dst;
    if (g < 131072){                           // X part: s = g>>16
        int s = g >> 16;
        int E = (g & 65535)*8;                 // element offset within scale
        int blk = E >> 9, lane8 = (E >> 3) & 63;
        int row = (blk>>3)*16 + (lane8 & 15);
        int ci  = (blk&7)*32 + (lane8>>4)*8;
        src = (s ? x1 : x0) + (size_t)row*256 + ci;
        dst = Xb + (size_t)s*524288 + E;
    } else {
        int gw = g - 131072;                   // W part: sp = gw>>13
        int sp = gw >> 13;
        int E = (gw & 8191)*8;
        int blk = E >> 9, lane8 = (E >> 3) & 63;
        int co = (blk>>3)*16 + (lane8 & 15);
        int ci = (blk&7)*32 + (lane8>>4)*8;
        src = args.W[sp] + (size_t)co*256 + ci;
        dst = Wb + (size_t)sp*65536 + E;
    }
    f32x4 a = *reinterpret_cast<const f32x4*>(src);
    f32x4 b = *reinterpret_cast<const f32x4*>(src+4);
    bf16x8 o;
    #pragma unroll
    for (int j=0;j<4;j++){ o[j] = (__bf16)a[j]; o[4+j] = (__bf16)b[j]; }
    *reinterpret_cast<bf16x8*>(dst) = o;
}

// ---------------- projection ----------------
// Each block computes a 64x64 tile of q|k|v, stages in LDS (fragment order
// for q/k, natural for v), writes ONE contiguous 8KB region.
__global__ __launch_bounds__(256) void proj_k(const __bf16* __restrict__ Xb,
                                              const __bf16* __restrict__ Wb,
                                              ProjArgs args,
                                              __bf16* __restrict__ Qb,
                                              __bf16* __restrict__ Kb,
                                              __bf16* __restrict__ Vb)
{
    __shared__ __bf16 stage[4096];
    int bid = blockIdx.x;
    int cg = bid % 12, rg = bid / 12;
    int tid = threadIdx.x, wv = tid >> 6, l = tid & 63;
    int lr = l & 15, lg = l >> 4;
    int s = rg >> 5;
    const __bf16* Xf = Xb + (size_t)s*524288;
    int p = cg >> 2;                       // 0=q 1=k 2=v
    const __bf16* Wf = Wb + (size_t)(s*3+p)*65536;
    const float* bp = args.Bz[s*3 + p];
    int colbase = (cg & 3)*64;
    int rowblk = ((rg & 31)*4 + wv);

    f32x4 acc[4];
    #pragma unroll
    for (int t=0;t<4;t++) acc[t] = f32x4{0.f,0.f,0.f,0.f};

    #pragma unroll
    for (int kk=0; kk<8; kk++){
        bf16x8 af = ld8(Xf + (size_t)(rowblk*8 + kk)*512 + l*8);
        #pragma unroll
        for (int ct=0; ct<4; ct++){
            bf16x8 bfv = ld8(Wf + (size_t)(((cg&3)*4 + ct)*8 + kk)*512 + l*8);
            acc[ct] = MFMA16(af, bfv, acc[ct]);
        }
    }
    float qs = (p==0) ? 0.09016844136f : 1.0f;   // (1/16)*log2(e) into Q
    #pragma unroll
    for (int ct=0; ct<4; ct++){
        int d = ct*16 + lr;                      // 0..63 within head
        float bias = bp[colbase + d];
        #pragma unroll
        for (int i=0;i<4;i++){
            float v = (acc[ct][i] + bias) * qs;
            int a;
            if (p < 2) a = wv*1024 + ((d>>5)&1)*512 + ((d>>3)&3)*128 + (lg*4+i)*8 + (d&7);
            else       a = (wv*16 + lg*4 + i)*64 + d;
            stage[a] = (__bf16)v;
        }
    }
    __syncthreads();
    int gr0 = rg*64;
    int b = (gr0 >> 10) & 1, n0 = gr0 & 1023;
    int h = cg & 3;
    int sb = s*2 + b;
    __bf16* dstb; size_t goff;
    if (p == 0){ dstb = Qb; goff = ((size_t)(sb*4 + h))*65536 + (size_t)(n0>>4)*1024; }
    else if (p == 1){ dstb = Kb; goff = ((size_t)(sb*4 + h))*65536 + (size_t)(n0>>4)*1024; }
    else { dstb = Vb; goff = ((size_t)(sb*4 + h)*1024 + n0)*64; }
    bf16x8 v0 = *reinterpret_cast<const bf16x8*>(stage + tid*16);
    bf16x8 v1 = *reinterpret_cast<const bf16x8*>(stage + tid*16 + 8);
    *reinterpret_cast<bf16x8*>(dstb + goff + (size_t)tid*16)     = v0;
    *reinterpret_cast<bf16x8*>(dstb + goff + (size_t)tid*16 + 8) = v1;
}

// ------ smoothed V^T, sigma-permuted A-fragment order: Wsig[sbu] ------
__global__ __launch_bounds__(256) void smooth_k(const __bf16* __restrict__ Vb,
                                                __bf16* __restrict__ WT)
{
    __shared__ __bf16 Vt[72][66];
    int bid = blockIdx.x;
    int sbu = bid >> 4, n0 = (bid & 15)*64;
    int tid = threadIdx.x;
    const __bf16* Vs = Vb + (size_t)sbu*65536;
    for (int idx = tid; idx < 576; idx += 256){
        int row = idx >> 3, ch = idx & 7;
        int n = (n0 - 4 + row) & 1023;
        bf16x8 v = ld8(Vs + (size_t)n*64 + ch*8);
        #pragma unroll
        for (int j=0;j<8;j++) Vt[row][ch*8+j] = v[j];
    }
    __syncthreads();
    int w = tid >> 6, l = tid & 63;
    __bf16* dst = WT + (size_t)sbu*65536;
    int m = n0 + l;
    int kb = m >> 5, m32 = m & 31;
    int p = (m32 < 16) ? ((m32>>2)*8 + (m32&3))
                       : (((m32-16)>>2)*8 + 4 + (m32&3));
    size_t pbase = (size_t)kb*2048 + (p>>3)*128 + (p&7);
    #pragma unroll
    for (int it=0; it<16; it++){
        int d = it*4 + w;
        float sum = 0.f;
        #pragma unroll
        for (int j=0;j<5;j++) sum += (float)Vt[l + j*2][d];
        dst[pbase + (size_t)(d>>4)*512 + (d&15)*8] = (__bf16)sum;
    }
}

// ---------------- attention (swapped operands, full-K, normalized out) -------
// Block task = (s,b,h,dhi,qg): 4 waves x 32 q-rows, 1024 keys.
// Manual register double-buffer; barrier each 64 keys keeps the 4 waves
// (which read the SAME K/W stream) converged -> L1 dedupe.
#define LOADT(KP, WP, kt) { \
    const __bf16* k0_ = Kg + (size_t)((kt)>>4)*1024 + l*8; \
    KP##0 = ld8(k0_);        KP##1 = ld8(k0_ + 512); \
    KP##2 = ld8(k0_ + 1024); KP##3 = ld8(k0_ + 1536); \
    const __bf16* w0_ = Wu + (size_t)((kt)>>5)*2048 + l*8; \
    WP##0 = ld8(w0_);        WP##1 = ld8(w0_ + 512); \
    WP##2 = ld8(w0_ + 1024); WP##3 = ld8(w0_ + 1536); }

#define COMPUTE(KP, WP) { \
    f32x4 sA0 = MFMA16(KP##0, qa0, z); sA0 = MFMA16(KP##1, qa1, sA0); \
    f32x4 sA1 = MFMA16(KP##2, qa0, z); sA1 = MFMA16(KP##3, qa1, sA1); \
    f32x4 sB0 = MFMA16(KP##0, qb0, z); sB0 = MFMA16(KP##1, qb1, sB0); \
    f32x4 sB1 = MFMA16(KP##2, qb0, z); sB1 = MFMA16(KP##3, qb1, sB1); \
    bf16x8 paA, paB; \
    _Pragma("unroll") \
    for (int i=0;i<4;i++){ \
        float eA0 = __builtin_amdgcn_exp2f(sA0[i]); \
        float eA1 = __builtin_amdgcn_exp2f(sA1[i]); \
        float eB0 = __builtin_amdgcn_exp2f(sB0[i]); \
        float eB1 = __builtin_amdgcn_exp2f(sB1[i]); \
        dsA += eA0 + eA1; dsB += eB0 + eB1; \
        paA[i] = (__bf16)eA0; paA[4+i] = (__bf16)eA1; \
        paB[i] = (__bf16)eB0; paB[4+i] = (__bf16)eB1; \
    } \
    pvA[0] = MFMA16(WP##0, paA, pvA[0]); \
    pvA[1] = MFMA16(WP##1, paA, pvA[1]); \
    pvA[2] = MFMA16(WP##2, paA, pvA[2]); \
    pvA[3] = MFMA16(WP##3, paA, pvA[3]); \
    pvB[0] = MFMA16(WP##0, paB, pvB[0]); \
    pvB[1] = MFMA16(WP##1, paB, pvB[1]); \
    pvB[2] = MFMA16(WP##2, paB, pvB[2]); \
    pvB[3] = MFMA16(WP##3, paB, pvB[3]); }

__global__ __launch_bounds__(256) void attn_k(const __bf16* __restrict__ Qb,
                                              const __bf16* __restrict__ Kb,
                                              const __bf16* __restrict__ WT,
                                              __bf16* __restrict__ pvp)
{
    int tid = threadIdx.x, wv = tid>>6, l = tid&63, lr = l&15, lg = l>>4;
    int t = blockIdx.x;
    int qg = t & 7; t >>= 3;
    int dhi = t & 3, h = (t>>2)&3, b = (t>>4)&1, s = (t>>5)&1;
    int dhv = (dhi==2) ? -1 : (dhi==3 ? 2 : dhi);   // {0,1,-1,2}
    int g = (h - dhv + 4) & 3;                      // K head
    int u = (h + dhv + 4) & 3;                      // V head
    int sb = s*2 + b;
    int nbase = qg*128 + wv*32;
    const __bf16* Qw = Qb + ((size_t)(sb*4 + h))*65536 + (size_t)(nbase>>4)*1024;
    const __bf16* Kg = Kb + ((size_t)(sb*4 + g))*65536;
    const __bf16* Wu = WT + ((size_t)(sb*4 + u))*65536;
    bf16x8 qa0 = ld8(Qw + l*8),        qa1 = ld8(Qw + 512 + l*8);
    bf16x8 qb0 = ld8(Qw + 1024 + l*8), qb1 = ld8(Qw + 1536 + l*8);

    const f32x4 z = {0.f,0.f,0.f,0.f};
    f32x4 pvA[4] = {z,z,z,z};
    f32x4 pvB[4] = {z,z,z,z};
    float dsA = 0.f, dsB = 0.f;

    bf16x8 kA0,kA1,kA2,kA3, wA0,wA1,wA2,wA3;
    bf16x8 kX0,kX1,kX2,kX3, wX0,wX1,wX2,wX3;
    LOADT(kA, wA, 0)
    for (int kt=0; kt<1024; kt+=64){
        LOADT(kX, wX, kt+32)          // issue next half-tile early
        COMPUTE(kA, wA)
        LOADT(kA, wA, kt+64)          // tail over-read (kt=960 -> 1024) lands
                                      // in the adjacent ws buffer: safe, unused
        COMPUTE(kX, wX)
        __syncthreads();              // keep 4 waves converged on shared stream
    }
    dsA += __shfl_xor(dsA, 16, 64); dsA += __shfl_xor(dsA, 32, 64);
    dsB += __shfl_xor(dsB, 16, 64); dsB += __shfl_xor(dsB, 32, 64);
    float wgt = (dhi==3) ? 2.f : 1.f;
    float invA = wgt / dsA, invB = wgt / dsB;

    // stage normalized O-tile (32 rows x 64 cols) in per-wave LDS, stride 72
    __shared__ alignas(16) __bf16 ost[4][32*72];
    __bf16* S = ost[wv];
    #pragma unroll
    for (int dt=0; dt<4; dt++){
        bf16x4 oA, oB;
        #pragma unroll
        for (int i=0;i<4;i++){ oA[i] = (__bf16)(pvA[dt][i]*invA); oB[i] = (__bf16)(pvB[dt][i]*invB); }
        int c0 = dt*16 + lg*4;
        *reinterpret_cast<bf16x4*>(S + lr*72 + c0)      = oA;
        *reinterpret_cast<bf16x4*>(S + (16+lr)*72 + c0) = oB;
    }
    int slot = s*4 + dhi;
    __bf16* pp = pvp + (size_t)slot*524288 + (size_t)b*262144 + (size_t)h*64;
    #pragma unroll
    for (int it=0; it<4; it++){
        int r = it*8 + (l>>3);
        bf16x8 v = *reinterpret_cast<const bf16x8*>(S + r*72 + (l&7)*8);
        *reinterpret_cast<bf16x8*>(pp + (size_t)(nbase + r)*256 + (l&7)*8) = v;
    }
}

// ------- reduce: out[b][n][c] = sum over 8 normalized slots ------------
__global__ __launch_bounds__(256) void reduce_k(const __bf16* __restrict__ pvp,
                                                float* __restrict__ out)
{
    int idx = blockIdx.x*256 + threadIdx.x;        // 0..65535
    size_t off = (size_t)idx*8;
    float acc[8] = {0,0,0,0,0,0,0,0};
    #pragma unroll
    for (int s4=0; s4<8; s4++){
        bf16x8 v = ld8(pvp + (size_t)s4*524288 + off);
        #pragma unroll
        for (int j=0;j<8;j++) acc[j] += (float)v[j];
    }
    f32x4 o0 = {acc[0],acc[1],acc[2],acc[3]};
    f32x4 o1 = {acc[4],acc[5],acc[6],acc[7]};
    *reinterpret_cast<f32x4*>(out + off)     = o0;
    *reinterpret_cast<f32x4*>(out + off + 4) = o1;
}

extern "C" void kernel_launch(void* const* d_in, const int* in_sizes, int n_in,
                              void* d_out, int out_size, void* d_ws, size_t ws_size,
                              hipStream_t stream)
{
    const float* x0 = (const float*)d_in[0];
    const float* x1 = (const float*)d_in[1];
    ProjArgs pa;
    for (int s=0;s<2;s++) for (int p=0;p<3;p++){
        pa.W[s*3+p]  = (const float*)d_in[2 + s*6 + p*2];
        pa.Bz[s*3+p] = (const float*)d_in[3 + s*6 + p*2];
    }
    char* wsb = (char*)d_ws;
    __bf16* Qb = (__bf16*)(wsb);                 // 2 MB (fragment order)
    __bf16* Kb = (__bf16*)(wsb + (2u<<20));      // 2 MB (fragment order)
    __bf16* Vb = (__bf16*)(wsb + (4u<<20));      // 2 MB (natural)
    __bf16* WT = (__bf16*)(wsb + (6u<<20));      // 2 MB (sigma fragment order)
    __bf16* Xb = (__bf16*)(wsb + (8u<<20));      // 2 MB (fragment order)
    __bf16* Wb = (__bf16*)(wsb + (10u<<20));     // 0.75 MB (fragment order)
    __bf16* pvp = (__bf16*)(wsb + (11u<<20));    // 8 MB (bf16, 8 normalized slots)

    cvt_k<<<704, 256, 0, stream>>>(x0, x1, pa, Xb, Wb);
    proj_k<<<768, 256, 0, stream>>>(Xb, Wb, pa, Qb, Kb, Vb);
    smooth_k<<<256, 256, 0, stream>>>(Vb, WT);
    attn_k<<<512, 256, 0, stream>>>(Qb, Kb, WT, pvp);
    reduce_k<<<256, 256, 0, stream>>>(pvp, (float*)d_out);
}